// Round 24
// baseline (126.411 us; speedup 1.0000x reference)
//
#include <hip/hip_runtime.h>
#include <math.h>

#define NTOK 65536
#define DIMD 128
#define KCB  2048
#define NSLAB 512   // one histogram slab per pass1 block

typedef unsigned short u16;
typedef __attribute__((ext_vector_type(8))) unsigned short u16x8;
typedef __attribute__((ext_vector_type(8))) __bf16 bf16x8;
typedef __attribute__((ext_vector_type(4))) float f32x4;

union U8 { u16x8 u; bf16x8 b; };

__device__ __forceinline__ u16 f2bf(float f) {
  union { float f; unsigned u; } c; c.f = f;
  unsigned r = c.u + 0x7FFFu + ((c.u >> 16) & 1u);
  return (u16)(r >> 16);
}
__device__ __forceinline__ float bf2f(u16 h) {
  union { unsigned u; float f; } c; c.u = ((unsigned)h) << 16;
  return c.f;
}

// linear tile staging: thread tid covers bytes [tid*16 + i*4096]; dest mirrors source
__device__ __forceinline__ void stage8(const char* srcLane, char* ldsWaveBase) {
  #pragma unroll
  for (int i = 0; i < 8; ++i)
    __builtin_amdgcn_global_load_lds((const __attribute__((address_space(1))) void*)(srcLane + i * 4096),
                                     (__attribute__((address_space(3))) void*)(ldsWaveBase + i * 4096), 16, 0, 0);
}

// ---------------- small kernels ----------------

// pack codebook to bf16 H+L in MFMA-fragment order, 64-code tiles (R8 layout); gid 0 zeroes acc
__global__ __launch_bounds__(256) void k_packcb(const float* __restrict__ cb, u16* __restrict__ cbp,
                                                float* __restrict__ acc4) {
  const int gid = blockIdx.x * 256 + threadIdx.x;
  if (gid == 0) { acc4[0] = 0.0f; acc4[1] = 0.0f; acc4[2] = 0.0f; acc4[3] = 0.0f; }
  if (gid >= 32768) return;
  const int lane = gid & 63;
  const int f = (gid >> 6) & 15;
  const int T = gid >> 10;
  const int ks = f >> 2, nf = f & 3;
  const int hi = lane >> 4, l15 = lane & 15;
  const int c = T * 64 + nf * 16 + l15;
  const int d0 = ks * 32 + hi * 8;
  const float4 v0 = *(const float4*)(cb + (size_t)c * DIMD + d0);
  const float4 v1 = *(const float4*)(cb + (size_t)c * DIMD + d0 + 4);
  const float e[8] = {v0.x, v0.y, v0.z, v0.w, v1.x, v1.y, v1.z, v1.w};
  union { u16 s[8]; u16x8 u; } oh, ol;
  #pragma unroll
  for (int i = 0; i < 8; ++i) {
    const u16 h = f2bf(e[i]);
    oh.s[i] = h;
    ol.s[i] = f2bf(e[i] - bf2f(h));
  }
  u16* tile = cbp + (size_t)T * 16384;
  *(u16x8*)(tile + (f * 64 + lane) * 8) = oh.u;
  *(u16x8*)(tile + 8192 + (f * 64 + lane) * 8) = ol.u;
}

// ---------------- MFMA pass 1: split precision, fused x-norm + gather + histogram + stats ----------------
// single-barrier pipeline with DEFERRED EPILOGUE: tile t's top-1 scan runs after tile t+1's
// MFMA burst is issued (independent work -> VALU hides under MFMA). Bit-identical results.

// MFMA burst for one tile from LDS base BASE into accumulator array ACC (zeroed here)
#define MFMA_TILE(ACC, BASE)                                                                     \
  do {                                                                                           \
    _Pragma("unroll")                                                                            \
    for (int m_ = 0; m_ < 2; ++m_)                                                               \
      _Pragma("unroll")                                                                          \
      for (int nf_ = 0; nf_ < 4; ++nf_) ACC[m_][nf_] = (f32x4){0.f, 0.f, 0.f, 0.f};             \
    __builtin_amdgcn_s_setprio(1);                                                               \
    _Pragma("unroll")                                                                            \
    for (int ks_ = 0; ks_ < 4; ++ks_) {                                                          \
      U8 bh_[4], bl_[4];                                                                         \
      _Pragma("unroll")                                                                          \
      for (int nf_ = 0; nf_ < 4; ++nf_) {                                                        \
        bh_[nf_].u = *(const u16x8*)((BASE) + ((ks_ * 4 + nf_) << 10));                          \
        bl_[nf_].u = *(const u16x8*)((BASE) + 16384 + ((ks_ * 4 + nf_) << 10));                  \
      }                                                                                          \
      _Pragma("unroll")                                                                          \
      for (int nf_ = 0; nf_ < 4; ++nf_) {                                                        \
        ACC[0][nf_] = __builtin_amdgcn_mfma_f32_16x16x32_bf16(Ah[0][ks_].b, bh_[nf_].b, ACC[0][nf_], 0, 0, 0); \
        ACC[1][nf_] = __builtin_amdgcn_mfma_f32_16x16x32_bf16(Ah[1][ks_].b, bh_[nf_].b, ACC[1][nf_], 0, 0, 0); \
      }                                                                                          \
      _Pragma("unroll")                                                                          \
      for (int nf_ = 0; nf_ < 4; ++nf_) {                                                        \
        ACC[0][nf_] = __builtin_amdgcn_mfma_f32_16x16x32_bf16(Al[0][ks_].b, bh_[nf_].b, ACC[0][nf_], 0, 0, 0); \
        ACC[1][nf_] = __builtin_amdgcn_mfma_f32_16x16x32_bf16(Al[1][ks_].b, bh_[nf_].b, ACC[1][nf_], 0, 0, 0); \
      }                                                                                          \
      _Pragma("unroll")                                                                          \
      for (int nf_ = 0; nf_ < 4; ++nf_) {                                                        \
        ACC[0][nf_] = __builtin_amdgcn_mfma_f32_16x16x32_bf16(Ah[0][ks_].b, bl_[nf_].b, ACC[0][nf_], 0, 0, 0); \
        ACC[1][nf_] = __builtin_amdgcn_mfma_f32_16x16x32_bf16(Ah[1][ks_].b, bl_[nf_].b, ACC[1][nf_], 0, 0, 0); \
      }                                                                                          \
    }                                                                                            \
    __builtin_amdgcn_s_setprio(0);                                                               \
  } while (0)

// per-lane top-1 epilogue for the tile with index TT over accumulator ACC
#define EPI_TILE(ACC, TT)                                                                        \
  do {                                                                                           \
    const int colbase_ = (TT) * 64 + l15;                                                        \
    _Pragma("unroll")                                                                            \
    for (int m_ = 0; m_ < 2; ++m_)                                                               \
      _Pragma("unroll")                                                                          \
      for (int rg_ = 0; rg_ < 4; ++rg_) {                                                        \
        const int r_ = m_ * 4 + rg_;                                                             \
        float vv_ = v1[r_];                                                                      \
        int kk_ = k1[r_];                                                                        \
        _Pragma("unroll")                                                                        \
        for (int nf_ = 0; nf_ < 4; ++nf_) {                                                      \
          const float xv_ = ACC[m_][nf_][rg_];                                                   \
          const bool gt_ = xv_ > vv_;                                                            \
          kk_ = gt_ ? (colbase_ + nf_ * 16) : kk_;                                               \
          vv_ = gt_ ? xv_ : vv_;                                                                 \
        }                                                                                        \
        v1[r_] = vv_; k1[r_] = kk_;                                                              \
      }                                                                                          \
  } while (0)

__global__ __launch_bounds__(256, 2) void k_pass1(const float* __restrict__ x, const float* __restrict__ mask,
                                                  const float* __restrict__ cb, const u16* __restrict__ cbp,
                                                  float* __restrict__ outQ, float* __restrict__ outEnc,
                                                  float* __restrict__ apPart, float* __restrict__ cnPart,
                                                  float* __restrict__ acc4) {
  __shared__ __align__(16) char Bsmem[65536];  // 2 x (16KB H + 16KB L); reused as histograms at tail
  const int tid = threadIdx.x;
  const int lane = tid & 63, w = tid >> 6;
  const int l15 = lane & 15, hi = lane >> 4;
  const int row0 = blockIdx.x * 128;
  const char* src = (const char*)cbp;

  // fused prep: load x f32, row-norm via 2-step shuffle (4 lanes/row), split to bf16 H+L in regs
  U8 Ah[2][4], Al[2][4];
  #pragma unroll
  for (int mf = 0; mf < 2; ++mf) {
    const int row = row0 + w * 32 + mf * 16 + l15;
    const float add = (1.0f - mask[row]) * 1e-6f;
    const float* xr = x + (size_t)row * DIMD + hi * 8;
    float xf[4][8];
    float ss = 0.f;
    #pragma unroll
    for (int ks = 0; ks < 4; ++ks) {
      const float4 a = *(const float4*)(xr + ks * 32);
      const float4 bq = *(const float4*)(xr + ks * 32 + 4);
      xf[ks][0] = a.x + add;  xf[ks][1] = a.y + add;  xf[ks][2] = a.z + add;  xf[ks][3] = a.w + add;
      xf[ks][4] = bq.x + add; xf[ks][5] = bq.y + add; xf[ks][6] = bq.z + add; xf[ks][7] = bq.w + add;
      #pragma unroll
      for (int e = 0; e < 8; ++e) ss = fmaf(xf[ks][e], xf[ks][e], ss);
    }
    ss += __shfl_xor(ss, 16, 64);
    ss += __shfl_xor(ss, 32, 64);
    const float sc = 1.0f / fmaxf(sqrtf(ss), 1e-6f);
    #pragma unroll
    for (int ks = 0; ks < 4; ++ks) {
      union { u16 s[8]; u16x8 u; } th, tl;
      #pragma unroll
      for (int e = 0; e < 8; ++e) {
        const float xn = xf[ks][e] * sc;
        const u16 h = f2bf(xn);
        th.s[e] = h;
        tl.s[e] = f2bf(xn - bf2f(h));
      }
      Ah[mf][ks].u = th.u;
      Al[mf][ks].u = tl.u;
    }
  }

  float v1[8];
  int k1[8];
  #pragma unroll
  for (int r = 0; r < 8; ++r) { v1[r] = -1e30f; k1[r] = 0; }

  f32x4 accA[2][4], accB[2][4];

  stage8(src + 0 * 32768 + tid * 16, Bsmem + 0 * 32768 + w * 1024);

  // prologue: tile 0 -> accA (no epilogue yet)
  asm volatile("s_waitcnt vmcnt(0)" ::: "memory");
  __builtin_amdgcn_sched_barrier(0);
  __builtin_amdgcn_s_barrier();
  __builtin_amdgcn_sched_barrier(0);
  stage8(src + 1 * 32768 + tid * 16, Bsmem + 1 * 32768 + w * 1024);
  MFMA_TILE(accA, Bsmem + 0 * 32768 + lane * 16);

  // steady state: odd tiles -> accB (epi accA), even tiles -> accA (epi accB)
  for (int tt = 1; tt < 32; tt += 2) {
    // tile tt (odd): buf1
    asm volatile("s_waitcnt vmcnt(0)" ::: "memory");
    __builtin_amdgcn_sched_barrier(0);
    __builtin_amdgcn_s_barrier();
    __builtin_amdgcn_sched_barrier(0);
    if (tt < 31)
      stage8(src + (size_t)(tt + 1) * 32768 + tid * 16, Bsmem + 0 * 32768 + w * 1024);
    MFMA_TILE(accB, Bsmem + 1 * 32768 + lane * 16);
    EPI_TILE(accA, tt - 1);

    // tile tt+1 (even): buf0
    if (tt + 1 < 32) {
      asm volatile("s_waitcnt vmcnt(0)" ::: "memory");
      __builtin_amdgcn_sched_barrier(0);
      __builtin_amdgcn_s_barrier();
      __builtin_amdgcn_sched_barrier(0);
      stage8(src + (size_t)(tt + 2) * 32768 + tid * 16, Bsmem + 1 * 32768 + w * 1024);
      MFMA_TILE(accA, Bsmem + 0 * 32768 + lane * 16);
      EPI_TILE(accB, tt);
    }
  }
  EPI_TILE(accB, 31);  // last odd tile's epilogue

  // ---- tail: reuse LDS as per-block histograms; merge + gather + stats ----
  __syncthreads();  // all waves done reading Bsmem (MFMA consumed all ds_reads)
  float* apLds = (float*)Bsmem;            // [KCB]
  float* cnLds = (float*)Bsmem + KCB;      // [KCB]
  float* smr = (float*)Bsmem + 2 * KCB;    // [12]
  for (int i = tid; i < 2 * KCB; i += 256) ((float*)Bsmem)[i] = 0.0f;
  __syncthreads();

  float msum = 0.f, slat = 0.f, sent = 0.f;
  #pragma unroll
  for (int m = 0; m < 2; ++m)
    #pragma unroll
    for (int rg = 0; rg < 4; ++rg) {
      const int r = m * 4 + rg;
      float a1 = v1[r];
      int ak = k1[r];
      #pragma unroll
      for (int off = 1; off <= 8; off <<= 1) {
        const float o1 = __shfl_xor(a1, off, 64);
        const int okk = __shfl_xor(ak, off, 64);
        const bool take = (o1 > a1) || (o1 == a1 && okk < ak);
        a1 = take ? o1 : a1;
        ak = take ? okk : ak;
      }
      const int row = row0 + w * 32 + m * 16 + hi * 4 + rg;
      const float mk = mask[row];
      // per-lane candidate weight vs merged max (same formula as before)
      float q = 0.f, qd = 0.f;
      if (v1[r] > a1 - 0.055f) {
        const float d = 200.f * (v1[r] - a1);
        q = __expf(d);
        qd = q * d;
      }
      float Z = q, S = qd;
      #pragma unroll
      for (int off = 1; off <= 8; off <<= 1) {
        Z += __shfl_xor(Z, off, 64);
        S += __shfl_xor(S, off, 64);
      }
      if (q > 0.f) atomicAdd(&apLds[k1[r]], mk * q / Z);
      // fused gather: 16 lanes write the selected codebook row (cb is L2-resident)
      const float4 g0 = *(const float4*)(cb + (size_t)ak * DIMD + l15 * 8);
      const float4 g1 = *(const float4*)(cb + (size_t)ak * DIMD + l15 * 8 + 4);
      *(float4*)(outQ + (size_t)row * DIMD + l15 * 8) = g0;
      *(float4*)(outQ + (size_t)row * DIMD + l15 * 8 + 4) = g1;
      if (l15 == 0) {
        atomicAdd(&cnLds[ak], mk);
        outEnc[row] = (float)ak;
        msum += mk;
        slat = fmaf(mk, 2.0f - 2.0f * a1, slat);
        sent = fmaf(mk, __logf(Z) - S / Z, sent);
      }
    }
  // block-reduce the three scalars (only l15==0 lanes hold nonzero)
  #pragma unroll
  for (int off = 32; off; off >>= 1) {
    msum += __shfl_xor(msum, off, 64);
    slat += __shfl_xor(slat, off, 64);
    sent += __shfl_xor(sent, off, 64);
  }
  if (lane == 0) { smr[w * 3] = msum; smr[w * 3 + 1] = slat; smr[w * 3 + 2] = sent; }
  __syncthreads();
  if (tid == 0) {
    float t0 = 0.f, t1 = 0.f, t2 = 0.f;
    #pragma unroll
    for (int v = 0; v < 4; ++v) { t0 += smr[v * 3]; t1 += smr[v * 3 + 1]; t2 += smr[v * 3 + 2]; }
    atomicAdd(&acc4[0], t0);
    atomicAdd(&acc4[1], t1);
    atomicAdd(&acc4[2], t2);
  }
  // write per-block histogram slabs (plain coalesced stores)
  float* apDst = apPart + (size_t)blockIdx.x * KCB;
  float* cnDst = cnPart + (size_t)blockIdx.x * KCB;
  for (int i = tid; i < KCB; i += 256) {
    apDst[i] = apLds[i];
    cnDst[i] = cnLds[i];
  }
}

// reduce partial slabs -> avgp-entropy partials + outCnt. 64 blocks x 256 threads, coalesced.
__global__ __launch_bounds__(256) void k_reduce(const float* __restrict__ apPart, const float* __restrict__ cnPart,
                                                const float* __restrict__ acc4In, float* __restrict__ outCnt,
                                                float* __restrict__ acc4) {
  __shared__ float sa8[8][32];
  __shared__ float sc8[8][32];
  const int tid = threadIdx.x;
  const int kloc = tid & 31, sg = tid >> 5;
  const int k = blockIdx.x * 32 + kloc;
  float sa = 0.f, sc = 0.f;
  #pragma unroll
  for (int i = 0; i < 64; ++i) {
    const int s = sg * 64 + i;
    sa += apPart[(size_t)s * KCB + k];
    sc += cnPart[(size_t)s * KCB + k];
  }
  sa8[sg][kloc] = sa;
  sc8[sg][kloc] = sc;
  __syncthreads();
  if (tid < 32) {
    float ta = 0.f, tc = 0.f;
    #pragma unroll
    for (int g = 0; g < 8; ++g) { ta += sa8[g][tid]; tc += sc8[g][tid]; }
    outCnt[blockIdx.x * 32 + tid] = tc;
    const float a = ta / acc4In[0];
    float ae = a * __logf(a + 1e-5f);
    #pragma unroll
    for (int off = 1; off <= 16; off <<= 1) ae += __shfl_xor(ae, off, 64);
    if (tid == 0) atomicAdd(&acc4[3], ae);
  }
}

__global__ __launch_bounds__(64) void k_final(const float* __restrict__ acc4, float* __restrict__ out3) {
  if (threadIdx.x == 0) {
    const float msum = acc4[0];
    const float lat = acc4[1] / (msum + 1e-6f);
    out3[0] = lat;
    out3[1] = lat;
    out3[2] = acc4[2] / msum + acc4[3];  // sample_entropy - avg_entropy
  }
}

// ---------------- launcher ----------------

extern "C" void kernel_launch(void* const* d_in, const int* in_sizes, int n_in,
                              void* d_out, int out_size, void* d_ws, size_t ws_size,
                              hipStream_t stream) {
  const float* x = (const float*)d_in[0];
  const float* mask = (const float*)d_in[1];
  const float* cb = (const float*)d_in[2];

  float* out = (float*)d_out;
  float* outQ = out;
  float* out3 = out + (size_t)NTOK * DIMD;
  float* outCnt = out3 + 3;
  float* outEnc = outCnt + KCB;

  float* ws = (float*)d_ws;
  float* acc4 = ws;                                       // 4
  u16* cbp = (u16*)(acc4 + 8);                            // K*D*2 u16 (1 MB)
  float* apPart = (float*)(cbp + (size_t)KCB * DIMD * 2); // NSLAB*K (4 MB)
  float* cnPart = apPart + (size_t)NSLAB * KCB;           // NSLAB*K (4 MB)

  k_packcb<<<32768 / 256, 256, 0, stream>>>(cb, cbp, acc4);
  k_pass1<<<NTOK / 128, 256, 0, stream>>>(x, mask, cb, cbp, outQ, outEnc, apPart, cnPart, acc4);
  k_reduce<<<64, 256, 0, stream>>>(apPart, cnPart, acc4, outCnt, acc4);
  k_final<<<1, 64, 0, stream>>>(acc4, out3);
}

// Round 25
// 124.390 us; speedup vs baseline: 1.0162x; 1.0162x over previous
//
#include <hip/hip_runtime.h>
#include <math.h>

#define NTOK 65536
#define DIMD 128
#define KCB  2048
#define NSLAB 512   // one histogram slab per pass1 block

typedef unsigned short u16;
typedef __attribute__((ext_vector_type(8))) unsigned short u16x8;
typedef __attribute__((ext_vector_type(8))) __bf16 bf16x8;
typedef __attribute__((ext_vector_type(4))) float f32x4;

union U8 { u16x8 u; bf16x8 b; };

__device__ __forceinline__ u16 f2bf(float f) {
  union { float f; unsigned u; } c; c.f = f;
  unsigned r = c.u + 0x7FFFu + ((c.u >> 16) & 1u);
  return (u16)(r >> 16);
}

// linear tile staging (16KB): thread tid covers bytes [tid*16 + i*4096]
__device__ __forceinline__ void stage4(const char* srcLane, char* ldsWaveBase) {
  #pragma unroll
  for (int i = 0; i < 4; ++i)
    __builtin_amdgcn_global_load_lds((const __attribute__((address_space(1))) void*)(srcLane + i * 4096),
                                     (__attribute__((address_space(3))) void*)(ldsWaveBase + i * 4096), 16, 0, 0);
}

// ---------------- small kernels ----------------

// pack codebook to plain bf16 in MFMA-fragment order, 64-code tiles, H only; gid 0 zeroes acc
__global__ __launch_bounds__(256) void k_packcb(const float* __restrict__ cb, u16* __restrict__ cbp,
                                                float* __restrict__ acc4) {
  const int gid = blockIdx.x * 256 + threadIdx.x;
  if (gid == 0) { acc4[0] = 0.0f; acc4[1] = 0.0f; acc4[2] = 0.0f; acc4[3] = 0.0f; }
  if (gid >= 32768) return;
  const int lane = gid & 63;
  const int f = (gid >> 6) & 15;
  const int T = gid >> 10;
  const int ks = f >> 2, nf = f & 3;
  const int hi = lane >> 4, l15 = lane & 15;
  const int c = T * 64 + nf * 16 + l15;
  const int d0 = ks * 32 + hi * 8;
  const float4 v0 = *(const float4*)(cb + (size_t)c * DIMD + d0);
  const float4 v1 = *(const float4*)(cb + (size_t)c * DIMD + d0 + 4);
  const float e[8] = {v0.x, v0.y, v0.z, v0.w, v1.x, v1.y, v1.z, v1.w};
  union { u16 s[8]; u16x8 u; } oh;
  #pragma unroll
  for (int i = 0; i < 8; ++i) oh.s[i] = f2bf(e[i]);
  u16* tile = cbp + (size_t)T * 8192;
  *(u16x8*)(tile + (f * 64 + lane) * 8) = oh.u;
}

// ---------------- MFMA pass 1: plain bf16 sweep, per-lane top-2, exact refine in tail ----------------

__global__ __launch_bounds__(256, 4) void k_pass1(const float* __restrict__ x, const float* __restrict__ mask,
                                                  const float* __restrict__ cb, const u16* __restrict__ cbp,
                                                  float* __restrict__ outQ, float* __restrict__ outEnc,
                                                  float* __restrict__ apPart, float* __restrict__ cnPart,
                                                  float* __restrict__ acc4) {
  __shared__ __align__(16) char Bsmem[32768];  // 2 x 16KB H tiles; reused as histograms at tail
  const int tid = threadIdx.x;
  const int lane = tid & 63, w = tid >> 6;
  const int l15 = lane & 15, hi = lane >> 4;
  const int row0 = blockIdx.x * 128;
  const char* src = (const char*)cbp;

  // fused prep: load x f32, row-norm via 2-step shuffle (4 lanes/row), to plain bf16 in regs
  U8 Ah[2][4];
  #pragma unroll
  for (int mf = 0; mf < 2; ++mf) {
    const int row = row0 + w * 32 + mf * 16 + l15;
    const float add = (1.0f - mask[row]) * 1e-6f;
    const float* xr = x + (size_t)row * DIMD + hi * 8;
    float xf[4][8];
    float ss = 0.f;
    #pragma unroll
    for (int ks = 0; ks < 4; ++ks) {
      const float4 a = *(const float4*)(xr + ks * 32);
      const float4 bq = *(const float4*)(xr + ks * 32 + 4);
      xf[ks][0] = a.x + add;  xf[ks][1] = a.y + add;  xf[ks][2] = a.z + add;  xf[ks][3] = a.w + add;
      xf[ks][4] = bq.x + add; xf[ks][5] = bq.y + add; xf[ks][6] = bq.z + add; xf[ks][7] = bq.w + add;
      #pragma unroll
      for (int e = 0; e < 8; ++e) ss = fmaf(xf[ks][e], xf[ks][e], ss);
    }
    ss += __shfl_xor(ss, 16, 64);
    ss += __shfl_xor(ss, 32, 64);
    const float sc = 1.0f / fmaxf(sqrtf(ss), 1e-6f);
    #pragma unroll
    for (int ks = 0; ks < 4; ++ks) {
      union { u16 s[8]; u16x8 u; } th;
      #pragma unroll
      for (int e = 0; e < 8; ++e) th.s[e] = f2bf(xf[ks][e] * sc);
      Ah[mf][ks].u = th.u;
    }
  }

  float v1[8], v2[8];
  int k1[8], k2[8];
  #pragma unroll
  for (int r = 0; r < 8; ++r) { v1[r] = -1e30f; v2[r] = -1e30f; k1[r] = 0; k2[r] = 0; }

  stage4(src + 0 * 16384 + tid * 16, Bsmem + 0 * 16384 + w * 1024);

  for (int t = 0; t < 32; ++t) {
    const int b = t & 1;
    asm volatile("s_waitcnt vmcnt(0)" ::: "memory");
    __builtin_amdgcn_sched_barrier(0);
    __builtin_amdgcn_s_barrier();
    __builtin_amdgcn_sched_barrier(0);
    if (t < 31)
      stage4(src + (size_t)(t + 1) * 16384 + tid * 16, Bsmem + (b ^ 1) * 16384 + w * 1024);

    const char* base = Bsmem + b * 16384 + lane * 16;
    f32x4 acc[2][4];
    #pragma unroll
    for (int m = 0; m < 2; ++m)
      #pragma unroll
      for (int nf = 0; nf < 4; ++nf) acc[m][nf] = (f32x4){0.f, 0.f, 0.f, 0.f};

    __builtin_amdgcn_s_setprio(1);
    #pragma unroll
    for (int ks = 0; ks < 4; ++ks) {
      #pragma unroll
      for (int nf = 0; nf < 4; ++nf) {
        U8 bh;
        bh.u = *(const u16x8*)(base + ((ks * 4 + nf) << 10));
        acc[0][nf] = __builtin_amdgcn_mfma_f32_16x16x32_bf16(Ah[0][ks].b, bh.b, acc[0][nf], 0, 0, 0);
        acc[1][nf] = __builtin_amdgcn_mfma_f32_16x16x32_bf16(Ah[1][ks].b, bh.b, acc[1][nf], 0, 0, 0);
      }
    }
    __builtin_amdgcn_s_setprio(0);

    // epilogue: PER-LANE top-2 (branchless; registers only; overlaps in-flight prefetch)
    const int colbase = t * 64 + l15;
    #pragma unroll
    for (int m = 0; m < 2; ++m)
      #pragma unroll
      for (int rg = 0; rg < 4; ++rg) {
        const int r = m * 4 + rg;
        float vv1 = v1[r], vv2 = v2[r];
        int kk1 = k1[r], kk2 = k2[r];
        #pragma unroll
        for (int nf = 0; nf < 4; ++nf) {
          const float xv = acc[m][nf][rg];
          const int idx = colbase + nf * 16;
          const bool g1 = xv > vv1;
          kk2 = g1 ? kk1 : ((xv > vv2) ? idx : kk2);
          vv2 = g1 ? vv1 : fmaxf(xv, vv2);
          kk1 = g1 ? idx : kk1;
          vv1 = fmaxf(vv1, xv);
        }
        v1[r] = vv1; v2[r] = vv2; k1[r] = kk1; k2[r] = kk2;
      }
  }

  // ---- tail: exact refine + histograms (LDS reused) ----
  __syncthreads();
  float* apLds = (float*)Bsmem;            // [KCB] 8KB
  float* cnLds = (float*)Bsmem + KCB;      // [KCB] 8KB
  float* smr = (float*)Bsmem + 2 * KCB;    // [12]
  for (int i = tid; i < 2 * KCB; i += 256) ((float*)Bsmem)[i] = 0.0f;
  __syncthreads();

  float msum = 0.f, slat = 0.f, sent = 0.f;
  #pragma unroll
  for (int m = 0; m < 2; ++m)
    #pragma unroll
    for (int rg = 0; rg < 4; ++rg) {
      const int r = m * 4 + rg;
      // bf16 max across the 16-lane group
      float a1 = v1[r];
      #pragma unroll
      for (int off = 1; off <= 8; off <<= 1) a1 = fmaxf(a1, __shfl_xor(a1, off, 64));
      const int row = row0 + w * 32 + m * 16 + hi * 4 + rg;
      const float mk = mask[row];
      const float add = (1.0f - mk) * 1e-6f;
      // reload x slice (8 dims/lane) + norm scale
      const float* xr = x + (size_t)row * DIMD + l15 * 8;
      const float4 xa = *(const float4*)xr;
      const float4 xb = *(const float4*)(xr + 4);
      float xs0[8] = {xa.x + add, xa.y + add, xa.z + add, xa.w + add,
                      xb.x + add, xb.y + add, xb.z + add, xb.w + add};
      float ss = 0.f;
      #pragma unroll
      for (int e = 0; e < 8; ++e) ss = fmaf(xs0[e], xs0[e], ss);
      #pragma unroll
      for (int off = 1; off <= 8; off <<= 1) ss += __shfl_xor(ss, off, 64);
      const float sc = 1.0f / fmaxf(sqrtf(ss), 1e-6f);
      // exact re-score of candidates within refine threshold of bf16 max
      const float RT = 4e-3f;
      const bool f1 = v1[r] > a1 - RT;
      const bool f2 = v2[r] > a1 - RT;
      const unsigned long long b1 = __ballot(f1);
      const unsigned long long b2 = __ballot(f2);
      unsigned m1 = (unsigned)((b1 >> (hi * 16)) & 0xFFFFull);
      unsigned m2 = (unsigned)((b2 >> (hi * 16)) & 0xFFFFull);
      float bestd = -1e30f;
      int bestk = 0x7fffffff;
      while (m1) {
        const int s = __builtin_ctz(m1); m1 &= m1 - 1;
        const int kc = __shfl(k1[r], (hi << 4) | s, 64);
        const float* cr = cb + (size_t)kc * DIMD + l15 * 8;
        const float4 ca = *(const float4*)cr;
        const float4 cbv = *(const float4*)(cr + 4);
        float d = xs0[0] * ca.x;
        d = fmaf(xs0[1], ca.y, d); d = fmaf(xs0[2], ca.z, d); d = fmaf(xs0[3], ca.w, d);
        d = fmaf(xs0[4], cbv.x, d); d = fmaf(xs0[5], cbv.y, d);
        d = fmaf(xs0[6], cbv.z, d); d = fmaf(xs0[7], cbv.w, d);
        #pragma unroll
        for (int off = 1; off <= 8; off <<= 1) d += __shfl_xor(d, off, 64);
        if (d > bestd || (d == bestd && kc < bestk)) { bestd = d; bestk = kc; }
      }
      while (m2) {
        const int s = __builtin_ctz(m2); m2 &= m2 - 1;
        const int kc = __shfl(k2[r], (hi << 4) | s, 64);
        const float* cr = cb + (size_t)kc * DIMD + l15 * 8;
        const float4 ca = *(const float4*)cr;
        const float4 cbv = *(const float4*)(cr + 4);
        float d = xs0[0] * ca.x;
        d = fmaf(xs0[1], ca.y, d); d = fmaf(xs0[2], ca.z, d); d = fmaf(xs0[3], ca.w, d);
        d = fmaf(xs0[4], cbv.x, d); d = fmaf(xs0[5], cbv.y, d);
        d = fmaf(xs0[6], cbv.z, d); d = fmaf(xs0[7], cbv.w, d);
        #pragma unroll
        for (int off = 1; off <= 8; off <<= 1) d += __shfl_xor(d, off, 64);
        if (d > bestd || (d == bestd && kc < bestk)) { bestd = d; bestk = kc; }
      }
      const float bestv = bestd * sc;  // exact normalized score of chosen code
      // histogram weights from bf16 per-lane top-1 (same as before; loose-threshold outputs)
      float q = 0.f, qd = 0.f;
      if (v1[r] > a1 - 0.055f) {
        const float d = 200.f * (v1[r] - a1);
        q = __expf(d);
        qd = q * d;
      }
      float Z = q, S = qd;
      #pragma unroll
      for (int off = 1; off <= 8; off <<= 1) {
        Z += __shfl_xor(Z, off, 64);
        S += __shfl_xor(S, off, 64);
      }
      if (q > 0.f) atomicAdd(&apLds[k1[r]], mk * q / Z);
      // gather the exact-argmax codebook row
      const float4 g0 = *(const float4*)(cb + (size_t)bestk * DIMD + l15 * 8);
      const float4 g1 = *(const float4*)(cb + (size_t)bestk * DIMD + l15 * 8 + 4);
      *(float4*)(outQ + (size_t)row * DIMD + l15 * 8) = g0;
      *(float4*)(outQ + (size_t)row * DIMD + l15 * 8 + 4) = g1;
      if (l15 == 0) {
        atomicAdd(&cnLds[bestk], mk);
        outEnc[row] = (float)bestk;
        msum += mk;
        slat = fmaf(mk, 2.0f - 2.0f * bestv, slat);
        sent = fmaf(mk, __logf(Z) - S / Z, sent);
      }
    }
  // block-reduce the three scalars (only l15==0 lanes hold nonzero)
  #pragma unroll
  for (int off = 32; off; off >>= 1) {
    msum += __shfl_xor(msum, off, 64);
    slat += __shfl_xor(slat, off, 64);
    sent += __shfl_xor(sent, off, 64);
  }
  if (lane == 0) { smr[w * 3] = msum; smr[w * 3 + 1] = slat; smr[w * 3 + 2] = sent; }
  __syncthreads();
  if (tid == 0) {
    float t0 = 0.f, t1 = 0.f, t2 = 0.f;
    #pragma unroll
    for (int v = 0; v < 4; ++v) { t0 += smr[v * 3]; t1 += smr[v * 3 + 1]; t2 += smr[v * 3 + 2]; }
    atomicAdd(&acc4[0], t0);
    atomicAdd(&acc4[1], t1);
    atomicAdd(&acc4[2], t2);
  }
  // write per-block histogram slabs (plain coalesced stores)
  float* apDst = apPart + (size_t)blockIdx.x * KCB;
  float* cnDst = cnPart + (size_t)blockIdx.x * KCB;
  for (int i = tid; i < KCB; i += 256) {
    apDst[i] = apLds[i];
    cnDst[i] = cnLds[i];
  }
}

// reduce partial slabs -> avgp-entropy partials + outCnt. 64 blocks x 256 threads, coalesced.
__global__ __launch_bounds__(256) void k_reduce(const float* __restrict__ apPart, const float* __restrict__ cnPart,
                                                const float* __restrict__ acc4In, float* __restrict__ outCnt,
                                                float* __restrict__ acc4) {
  __shared__ float sa8[8][32];
  __shared__ float sc8[8][32];
  const int tid = threadIdx.x;
  const int kloc = tid & 31, sg = tid >> 5;
  const int k = blockIdx.x * 32 + kloc;
  float sa = 0.f, sc = 0.f;
  #pragma unroll
  for (int i = 0; i < 64; ++i) {
    const int s = sg * 64 + i;
    sa += apPart[(size_t)s * KCB + k];
    sc += cnPart[(size_t)s * KCB + k];
  }
  sa8[sg][kloc] = sa;
  sc8[sg][kloc] = sc;
  __syncthreads();
  if (tid < 32) {
    float ta = 0.f, tc = 0.f;
    #pragma unroll
    for (int g = 0; g < 8; ++g) { ta += sa8[g][tid]; tc += sc8[g][tid]; }
    outCnt[blockIdx.x * 32 + tid] = tc;
    const float a = ta / acc4In[0];
    float ae = a * __logf(a + 1e-5f);
    #pragma unroll
    for (int off = 1; off <= 16; off <<= 1) ae += __shfl_xor(ae, off, 64);
    if (tid == 0) atomicAdd(&acc4[3], ae);
  }
}

__global__ __launch_bounds__(64) void k_final(const float* __restrict__ acc4, float* __restrict__ out3) {
  if (threadIdx.x == 0) {
    const float msum = acc4[0];
    const float lat = acc4[1] / (msum + 1e-6f);
    out3[0] = lat;
    out3[1] = lat;
    out3[2] = acc4[2] / msum + acc4[3];  // sample_entropy - avg_entropy
  }
}

// ---------------- launcher ----------------

extern "C" void kernel_launch(void* const* d_in, const int* in_sizes, int n_in,
                              void* d_out, int out_size, void* d_ws, size_t ws_size,
                              hipStream_t stream) {
  const float* x = (const float*)d_in[0];
  const float* mask = (const float*)d_in[1];
  const float* cb = (const float*)d_in[2];

  float* out = (float*)d_out;
  float* outQ = out;
  float* out3 = out + (size_t)NTOK * DIMD;
  float* outCnt = out3 + 3;
  float* outEnc = outCnt + KCB;

  float* ws = (float*)d_ws;
  float* acc4 = ws;                                       // 4
  u16* cbp = (u16*)(acc4 + 8);                            // K*D u16 (512 KB, H only)
  float* apPart = (float*)(cbp + (size_t)KCB * DIMD);     // NSLAB*K (4 MB)
  float* cnPart = apPart + (size_t)NSLAB * KCB;           // NSLAB*K (4 MB)

  k_packcb<<<32768 / 256, 256, 0, stream>>>(cb, cbp, acc4);
  k_pass1<<<NTOK / 128, 256, 0, stream>>>(x, mask, cb, cbp, outQ, outEnc, apPart, cnPart, acc4);
  k_reduce<<<64, 256, 0, stream>>>(apPart, cnPart, acc4, outCnt, acc4);
  k_final<<<1, 64, 0, stream>>>(acc4, out3);
}

// Round 26
// 104.321 us; speedup vs baseline: 1.2118x; 1.1924x over previous
//
#include <hip/hip_runtime.h>
#include <math.h>

#define NTOK 65536
#define DIMD 128
#define KCB  2048
#define NSLAB 512   // one histogram slab per pass1 block

typedef unsigned short u16;
typedef __attribute__((ext_vector_type(8))) unsigned short u16x8;
typedef __attribute__((ext_vector_type(8))) __bf16 bf16x8;
typedef __attribute__((ext_vector_type(4))) float f32x4;

union U8 { u16x8 u; bf16x8 b; };

__device__ __forceinline__ u16 f2bf(float f) {
  union { float f; unsigned u; } c; c.f = f;
  unsigned r = c.u + 0x7FFFu + ((c.u >> 16) & 1u);
  return (u16)(r >> 16);
}
__device__ __forceinline__ float keyval(int k) {
  union { int i; float f; } c; c.i = k & 0xFFFFF800;
  return c.f;
}
__device__ __forceinline__ int imax(int a, int b) { return a > b ? a : b; }
__device__ __forceinline__ int imin(int a, int b) { return a < b ? a : b; }

// linear tile staging (16KB): thread tid covers bytes [tid*16 + i*4096]
__device__ __forceinline__ void stage4(const char* srcLane, char* ldsWaveBase) {
  #pragma unroll
  for (int i = 0; i < 4; ++i)
    __builtin_amdgcn_global_load_lds((const __attribute__((address_space(1))) void*)(srcLane + i * 4096),
                                     (__attribute__((address_space(3))) void*)(ldsWaveBase + i * 4096), 16, 0, 0);
}

// ---------------- small kernels ----------------

// pack codebook to plain bf16 in MFMA-fragment order, 64-code tiles, H only; gid 0 zeroes acc
__global__ __launch_bounds__(256) void k_packcb(const float* __restrict__ cb, u16* __restrict__ cbp,
                                                float* __restrict__ acc4) {
  const int gid = blockIdx.x * 256 + threadIdx.x;
  if (gid == 0) { acc4[0] = 0.0f; acc4[1] = 0.0f; acc4[2] = 0.0f; acc4[3] = 0.0f; }
  if (gid >= 32768) return;
  const int lane = gid & 63;
  const int f = (gid >> 6) & 15;
  const int T = gid >> 10;
  const int ks = f >> 2, nf = f & 3;
  const int hi = lane >> 4, l15 = lane & 15;
  const int c = T * 64 + nf * 16 + l15;
  const int d0 = ks * 32 + hi * 8;
  const float4 v0 = *(const float4*)(cb + (size_t)c * DIMD + d0);
  const float4 v1 = *(const float4*)(cb + (size_t)c * DIMD + d0 + 4);
  const float e[8] = {v0.x, v0.y, v0.z, v0.w, v1.x, v1.y, v1.z, v1.w};
  union { u16 s[8]; u16x8 u; } oh;
  #pragma unroll
  for (int i = 0; i < 8; ++i) oh.s[i] = f2bf(e[i]);
  u16* tile = cbp + (size_t)T * 8192;
  *(u16x8*)(tile + (f * 64 + lane) * 8) = oh.u;
}

// ---------------- MFMA pass 1: plain bf16 sweep, index-packed int top-2, exact refine in tail ----------------

__global__ __launch_bounds__(256, 4) void k_pass1(const float* __restrict__ x, const float* __restrict__ mask,
                                                  const float* __restrict__ cb, const u16* __restrict__ cbp,
                                                  float* __restrict__ outQ, float* __restrict__ outEnc,
                                                  float* __restrict__ apPart, float* __restrict__ cnPart,
                                                  float* __restrict__ acc4) {
  __shared__ __align__(16) char Bsmem[32768];  // 2 x 16KB H tiles; reused as histograms at tail
  const int tid = threadIdx.x;
  const int lane = tid & 63, w = tid >> 6;
  const int l15 = lane & 15, hi = lane >> 4;
  const int row0 = blockIdx.x * 128;
  const char* src = (const char*)cbp;

  // fused prep: load x f32, row-norm via 2-step shuffle (4 lanes/row), to plain bf16 in regs
  U8 Ah[2][4];
  #pragma unroll
  for (int mf = 0; mf < 2; ++mf) {
    const int row = row0 + w * 32 + mf * 16 + l15;
    const float add = (1.0f - mask[row]) * 1e-6f;
    const float* xr = x + (size_t)row * DIMD + hi * 8;
    float xf[4][8];
    float ss = 0.f;
    #pragma unroll
    for (int ks = 0; ks < 4; ++ks) {
      const float4 a = *(const float4*)(xr + ks * 32);
      const float4 bq = *(const float4*)(xr + ks * 32 + 4);
      xf[ks][0] = a.x + add;  xf[ks][1] = a.y + add;  xf[ks][2] = a.z + add;  xf[ks][3] = a.w + add;
      xf[ks][4] = bq.x + add; xf[ks][5] = bq.y + add; xf[ks][6] = bq.z + add; xf[ks][7] = bq.w + add;
      #pragma unroll
      for (int e = 0; e < 8; ++e) ss = fmaf(xf[ks][e], xf[ks][e], ss);
    }
    ss += __shfl_xor(ss, 16, 64);
    ss += __shfl_xor(ss, 32, 64);
    const float sc = 1.0f / fmaxf(sqrtf(ss), 1e-6f);
    #pragma unroll
    for (int ks = 0; ks < 4; ++ks) {
      union { u16 s[8]; u16x8 u; } th;
      #pragma unroll
      for (int e = 0; e < 8; ++e) th.s[e] = f2bf(xf[ks][e] * sc);
      Ah[mf][ks].u = th.u;
    }
  }

  // index-packed top-2 keys: key = (asint(score) & ~2047) | code_index
  int kv1[8], kv2[8];
  #pragma unroll
  for (int r = 0; r < 8; ++r) { kv1[r] = 0x80000000; kv2[r] = 0x80000000; }

  stage4(src + 0 * 16384 + tid * 16, Bsmem + 0 * 16384 + w * 1024);

  for (int t = 0; t < 32; ++t) {
    const int b = t & 1;
    asm volatile("s_waitcnt vmcnt(0)" ::: "memory");
    __builtin_amdgcn_sched_barrier(0);
    __builtin_amdgcn_s_barrier();
    __builtin_amdgcn_sched_barrier(0);
    if (t < 31)
      stage4(src + (size_t)(t + 1) * 16384 + tid * 16, Bsmem + (b ^ 1) * 16384 + w * 1024);

    const char* base = Bsmem + b * 16384 + lane * 16;
    f32x4 acc[2][4];
    #pragma unroll
    for (int m = 0; m < 2; ++m)
      #pragma unroll
      for (int nf = 0; nf < 4; ++nf) acc[m][nf] = (f32x4){0.f, 0.f, 0.f, 0.f};

    __builtin_amdgcn_s_setprio(1);
    #pragma unroll
    for (int ks = 0; ks < 4; ++ks) {
      #pragma unroll
      for (int nf = 0; nf < 4; ++nf) {
        U8 bh;
        bh.u = *(const u16x8*)(base + ((ks * 4 + nf) << 10));
        acc[0][nf] = __builtin_amdgcn_mfma_f32_16x16x32_bf16(Ah[0][ks].b, bh.b, acc[0][nf], 0, 0, 0);
        acc[1][nf] = __builtin_amdgcn_mfma_f32_16x16x32_bf16(Ah[1][ks].b, bh.b, acc[1][nf], 0, 0, 0);
      }
    }
    __builtin_amdgcn_s_setprio(0);

    // epilogue: index-packed int top-2 (pure max/min tree; overlaps in-flight prefetch)
    const int base11 = t * 64 + l15;
    #pragma unroll
    for (int m = 0; m < 2; ++m)
      #pragma unroll
      for (int rg = 0; rg < 4; ++rg) {
        const int r = m * 4 + rg;
        int kk[4];
        #pragma unroll
        for (int nf = 0; nf < 4; ++nf) {
          union { float f; int i; } cv;
          cv.f = acc[m][nf][rg];
          kk[nf] = (cv.i & 0xFFFFF800) | (base11 + nf * 16);
        }
        const int h1 = imax(kk[0], kk[1]), lo1 = imin(kk[0], kk[1]);
        const int h2 = imax(kk[2], kk[3]), lo2 = imin(kk[2], kk[3]);
        const int t1 = imax(h1, h2);
        const int t2 = imax(imin(h1, h2), (h1 > h2) ? lo1 : lo2);
        kv2[r] = imax(imax(kv2[r], t2), imin(kv1[r], t1));
        kv1[r] = imax(kv1[r], t1);
      }
  }

  // ---- tail: exact refine + histograms (LDS reused) ----
  __syncthreads();
  float* apLds = (float*)Bsmem;            // [KCB] 8KB
  float* cnLds = (float*)Bsmem + KCB;      // [KCB] 8KB
  float* smr = (float*)Bsmem + 2 * KCB;    // [12]
  for (int i = tid; i < 2 * KCB; i += 256) ((float*)Bsmem)[i] = 0.0f;
  __syncthreads();

  float msum = 0.f, slat = 0.f, sent = 0.f;
  #pragma unroll
  for (int m = 0; m < 2; ++m)
    #pragma unroll
    for (int rg = 0; rg < 4; ++rg) {
      const int r = m * 4 + rg;
      // int max of keys across the 16-lane group = bf16 max (+idx tiebreak)
      int a1k = kv1[r];
      #pragma unroll
      for (int off = 1; off <= 8; off <<= 1) {
        const int ok = __shfl_xor(a1k, off, 64);
        a1k = ok > a1k ? ok : a1k;
      }
      const float a1val = keyval(a1k);
      const float val1 = keyval(kv1[r]);
      const float val2 = keyval(kv2[r]);
      const int row = row0 + w * 32 + m * 16 + hi * 4 + rg;
      const float mk = mask[row];
      const float add = (1.0f - mk) * 1e-6f;
      // reload x slice (8 dims/lane) + norm scale
      const float* xr = x + (size_t)row * DIMD + l15 * 8;
      const float4 xa = *(const float4*)xr;
      const float4 xb = *(const float4*)(xr + 4);
      float xs0[8] = {xa.x + add, xa.y + add, xa.z + add, xa.w + add,
                      xb.x + add, xb.y + add, xb.z + add, xb.w + add};
      float ss = 0.f;
      #pragma unroll
      for (int e = 0; e < 8; ++e) ss = fmaf(xs0[e], xs0[e], ss);
      #pragma unroll
      for (int off = 1; off <= 8; off <<= 1) ss += __shfl_xor(ss, off, 64);
      const float sc = 1.0f / fmaxf(sqrtf(ss), 1e-6f);
      // exact re-score of candidates within refine threshold of bf16 max
      const float RT = 4e-3f;
      const bool f1 = val1 > a1val - RT;
      const bool f2 = val2 > a1val - RT;
      const unsigned long long b1 = __ballot(f1);
      const unsigned long long b2 = __ballot(f2);
      unsigned m1 = (unsigned)((b1 >> (hi * 16)) & 0xFFFFull);
      unsigned m2 = (unsigned)((b2 >> (hi * 16)) & 0xFFFFull);
      float bestd = -1e30f;
      int bestk = 0x7fffffff;
      while (m1) {
        const int s = __builtin_ctz(m1); m1 &= m1 - 1;
        const int kc = __shfl(kv1[r], (hi << 4) | s, 64) & 2047;
        const float* cr = cb + (size_t)kc * DIMD + l15 * 8;
        const float4 ca = *(const float4*)cr;
        const float4 cbv = *(const float4*)(cr + 4);
        float d = xs0[0] * ca.x;
        d = fmaf(xs0[1], ca.y, d); d = fmaf(xs0[2], ca.z, d); d = fmaf(xs0[3], ca.w, d);
        d = fmaf(xs0[4], cbv.x, d); d = fmaf(xs0[5], cbv.y, d);
        d = fmaf(xs0[6], cbv.z, d); d = fmaf(xs0[7], cbv.w, d);
        #pragma unroll
        for (int off = 1; off <= 8; off <<= 1) d += __shfl_xor(d, off, 64);
        if (d > bestd || (d == bestd && kc < bestk)) { bestd = d; bestk = kc; }
      }
      while (m2) {
        const int s = __builtin_ctz(m2); m2 &= m2 - 1;
        const int kc = __shfl(kv2[r], (hi << 4) | s, 64) & 2047;
        const float* cr = cb + (size_t)kc * DIMD + l15 * 8;
        const float4 ca = *(const float4*)cr;
        const float4 cbv = *(const float4*)(cr + 4);
        float d = xs0[0] * ca.x;
        d = fmaf(xs0[1], ca.y, d); d = fmaf(xs0[2], ca.z, d); d = fmaf(xs0[3], ca.w, d);
        d = fmaf(xs0[4], cbv.x, d); d = fmaf(xs0[5], cbv.y, d);
        d = fmaf(xs0[6], cbv.z, d); d = fmaf(xs0[7], cbv.w, d);
        #pragma unroll
        for (int off = 1; off <= 8; off <<= 1) d += __shfl_xor(d, off, 64);
        if (d > bestd || (d == bestd && kc < bestk)) { bestd = d; bestk = kc; }
      }
      const float bestv = bestd * sc;  // exact normalized score of chosen code
      // histogram weights from bf16 per-lane top-1 (loose-threshold outputs)
      float q = 0.f, qd = 0.f;
      if (val1 > a1val - 0.055f) {
        const float d = 200.f * (val1 - a1val);
        q = __expf(d);
        qd = q * d;
      }
      float Z = q, S = qd;
      #pragma unroll
      for (int off = 1; off <= 8; off <<= 1) {
        Z += __shfl_xor(Z, off, 64);
        S += __shfl_xor(S, off, 64);
      }
      if (q > 0.f) atomicAdd(&apLds[kv1[r] & 2047], mk * q / Z);
      // gather the exact-argmax codebook row
      const float4 g0 = *(const float4*)(cb + (size_t)bestk * DIMD + l15 * 8);
      const float4 g1 = *(const float4*)(cb + (size_t)bestk * DIMD + l15 * 8 + 4);
      *(float4*)(outQ + (size_t)row * DIMD + l15 * 8) = g0;
      *(float4*)(outQ + (size_t)row * DIMD + l15 * 8 + 4) = g1;
      if (l15 == 0) {
        atomicAdd(&cnLds[bestk], mk);
        outEnc[row] = (float)bestk;
        msum += mk;
        slat = fmaf(mk, 2.0f - 2.0f * bestv, slat);
        sent = fmaf(mk, __logf(Z) - S / Z, sent);
      }
    }
  // block-reduce the three scalars (only l15==0 lanes hold nonzero)
  #pragma unroll
  for (int off = 32; off; off >>= 1) {
    msum += __shfl_xor(msum, off, 64);
    slat += __shfl_xor(slat, off, 64);
    sent += __shfl_xor(sent, off, 64);
  }
  if (lane == 0) { smr[w * 3] = msum; smr[w * 3 + 1] = slat; smr[w * 3 + 2] = sent; }
  __syncthreads();
  if (tid == 0) {
    float t0 = 0.f, t1 = 0.f, t2 = 0.f;
    #pragma unroll
    for (int v = 0; v < 4; ++v) { t0 += smr[v * 3]; t1 += smr[v * 3 + 1]; t2 += smr[v * 3 + 2]; }
    atomicAdd(&acc4[0], t0);
    atomicAdd(&acc4[1], t1);
    atomicAdd(&acc4[2], t2);
  }
  // write per-block histogram slabs (plain coalesced stores)
  float* apDst = apPart + (size_t)blockIdx.x * KCB;
  float* cnDst = cnPart + (size_t)blockIdx.x * KCB;
  for (int i = tid; i < KCB; i += 256) {
    apDst[i] = apLds[i];
    cnDst[i] = cnLds[i];
  }
}

// reduce partial slabs -> avgp-entropy partials + outCnt. 64 blocks x 256 threads, coalesced.
__global__ __launch_bounds__(256) void k_reduce(const float* __restrict__ apPart, const float* __restrict__ cnPart,
                                                const float* __restrict__ acc4In, float* __restrict__ outCnt,
                                                float* __restrict__ acc4) {
  __shared__ float sa8[8][32];
  __shared__ float sc8[8][32];
  const int tid = threadIdx.x;
  const int kloc = tid & 31, sg = tid >> 5;
  const int k = blockIdx.x * 32 + kloc;
  float sa = 0.f, sc = 0.f;
  #pragma unroll
  for (int i = 0; i < 64; ++i) {
    const int s = sg * 64 + i;
    sa += apPart[(size_t)s * KCB + k];
    sc += cnPart[(size_t)s * KCB + k];
  }
  sa8[sg][kloc] = sa;
  sc8[sg][kloc] = sc;
  __syncthreads();
  if (tid < 32) {
    float ta = 0.f, tc = 0.f;
    #pragma unroll
    for (int g = 0; g < 8; ++g) { ta += sa8[g][tid]; tc += sc8[g][tid]; }
    outCnt[blockIdx.x * 32 + tid] = tc;
    const float a = ta / acc4In[0];
    float ae = a * __logf(a + 1e-5f);
    #pragma unroll
    for (int off = 1; off <= 16; off <<= 1) ae += __shfl_xor(ae, off, 64);
    if (tid == 0) atomicAdd(&acc4[3], ae);
  }
}

__global__ __launch_bounds__(64) void k_final(const float* __restrict__ acc4, float* __restrict__ out3) {
  if (threadIdx.x == 0) {
    const float msum = acc4[0];
    const float lat = acc4[1] / (msum + 1e-6f);
    out3[0] = lat;
    out3[1] = lat;
    out3[2] = acc4[2] / msum + acc4[3];  // sample_entropy - avg_entropy
  }
}

// ---------------- launcher ----------------

extern "C" void kernel_launch(void* const* d_in, const int* in_sizes, int n_in,
                              void* d_out, int out_size, void* d_ws, size_t ws_size,
                              hipStream_t stream) {
  const float* x = (const float*)d_in[0];
  const float* mask = (const float*)d_in[1];
  const float* cb = (const float*)d_in[2];

  float* out = (float*)d_out;
  float* outQ = out;
  float* out3 = out + (size_t)NTOK * DIMD;
  float* outCnt = out3 + 3;
  float* outEnc = outCnt + KCB;

  float* ws = (float*)d_ws;
  float* acc4 = ws;                                       // 4
  u16* cbp = (u16*)(acc4 + 8);                            // K*D u16 (512 KB, H only)
  float* apPart = (float*)(cbp + (size_t)KCB * DIMD);     // NSLAB*K (4 MB)
  float* cnPart = apPart + (size_t)NSLAB * KCB;           // NSLAB*K (4 MB)

  k_packcb<<<32768 / 256, 256, 0, stream>>>(cb, cbp, acc4);
  k_pass1<<<NTOK / 128, 256, 0, stream>>>(x, mask, cb, cbp, outQ, outEnc, apPart, cnPart, acc4);
  k_reduce<<<64, 256, 0, stream>>>(apPart, cnPart, acc4, outCnt, acc4);
  k_final<<<1, 64, 0, stream>>>(acc4, out3);
}

// Round 27
// 97.106 us; speedup vs baseline: 1.3018x; 1.0743x over previous
//
#include <hip/hip_runtime.h>
#include <math.h>

#define NTOK 65536
#define DIMD 128
#define KCB  2048
#define NSLAB 512   // one histogram slab per pass1 block

typedef unsigned short u16;
typedef __attribute__((ext_vector_type(8))) unsigned short u16x8;
typedef __attribute__((ext_vector_type(8))) __bf16 bf16x8;
typedef __attribute__((ext_vector_type(4))) float f32x4;

union U8 { u16x8 u; bf16x8 b; };

__device__ __forceinline__ u16 f2bf(float f) {
  union { float f; unsigned u; } c; c.f = f;
  unsigned r = c.u + 0x7FFFu + ((c.u >> 16) & 1u);
  return (u16)(r >> 16);
}
__device__ __forceinline__ float keyval(int k) {
  union { int i; float f; } c; c.i = k & 0xFFFFF800;
  return c.f;
}
__device__ __forceinline__ int imax(int a, int b) { return a > b ? a : b; }
__device__ __forceinline__ int imin(int a, int b) { return a < b ? a : b; }

// linear tile staging (16KB) with 512 threads: thread tid covers bytes [tid*16 + i*8192]
__device__ __forceinline__ void stage2x(const char* srcLane, char* ldsWaveBase) {
  #pragma unroll
  for (int i = 0; i < 2; ++i)
    __builtin_amdgcn_global_load_lds((const __attribute__((address_space(1))) void*)(srcLane + i * 8192),
                                     (__attribute__((address_space(3))) void*)(ldsWaveBase + i * 8192), 16, 0, 0);
}

// ---------------- small kernels ----------------

// pack codebook to plain bf16 in MFMA-fragment order, 64-code tiles, H only; gid 0 zeroes acc
__global__ __launch_bounds__(256) void k_packcb(const float* __restrict__ cb, u16* __restrict__ cbp,
                                                float* __restrict__ acc4) {
  const int gid = blockIdx.x * 256 + threadIdx.x;
  if (gid == 0) { acc4[0] = 0.0f; acc4[1] = 0.0f; acc4[2] = 0.0f; acc4[3] = 0.0f; }
  if (gid >= 32768) return;
  const int lane = gid & 63;
  const int f = (gid >> 6) & 15;
  const int T = gid >> 10;
  const int ks = f >> 2, nf = f & 3;
  const int hi = lane >> 4, l15 = lane & 15;
  const int c = T * 64 + nf * 16 + l15;
  const int d0 = ks * 32 + hi * 8;
  const float4 v0 = *(const float4*)(cb + (size_t)c * DIMD + d0);
  const float4 v1 = *(const float4*)(cb + (size_t)c * DIMD + d0 + 4);
  const float e[8] = {v0.x, v0.y, v0.z, v0.w, v1.x, v1.y, v1.z, v1.w};
  union { u16 s[8]; u16x8 u; } oh;
  #pragma unroll
  for (int i = 0; i < 8; ++i) oh.s[i] = f2bf(e[i]);
  u16* tile = cbp + (size_t)T * 8192;
  *(u16x8*)(tile + (f * 64 + lane) * 8) = oh.u;
}

// ---------------- MFMA pass 1: plain bf16 sweep (8 waves x 16 rows), int top-2, exact refine ----------------

__global__ __launch_bounds__(512, 2) void k_pass1(const float* __restrict__ x, const float* __restrict__ mask,
                                                  const float* __restrict__ cb, const u16* __restrict__ cbp,
                                                  float* __restrict__ outQ, float* __restrict__ outEnc,
                                                  float* __restrict__ apPart, float* __restrict__ cnPart,
                                                  float* __restrict__ acc4) {
  __shared__ __align__(16) char Bsmem[32768];  // 2 x 16KB H tiles; reused as histograms at tail
  const int tid = threadIdx.x;
  const int lane = tid & 63, w = tid >> 6;     // 8 waves
  const int l15 = lane & 15, hi = lane >> 4;
  const int row0 = blockIdx.x * 128;
  const char* src = (const char*)cbp;

  // fused prep: wave owns 16 rows; lane l15 -> row, hi -> k-group; norm via 2-step shuffle
  U8 Ah[4];
  {
    const int row = row0 + w * 16 + l15;
    const float add = (1.0f - mask[row]) * 1e-6f;
    const float* xr = x + (size_t)row * DIMD + hi * 8;
    float xf[4][8];
    float ss = 0.f;
    #pragma unroll
    for (int ks = 0; ks < 4; ++ks) {
      const float4 a = *(const float4*)(xr + ks * 32);
      const float4 bq = *(const float4*)(xr + ks * 32 + 4);
      xf[ks][0] = a.x + add;  xf[ks][1] = a.y + add;  xf[ks][2] = a.z + add;  xf[ks][3] = a.w + add;
      xf[ks][4] = bq.x + add; xf[ks][5] = bq.y + add; xf[ks][6] = bq.z + add; xf[ks][7] = bq.w + add;
      #pragma unroll
      for (int e = 0; e < 8; ++e) ss = fmaf(xf[ks][e], xf[ks][e], ss);
    }
    ss += __shfl_xor(ss, 16, 64);
    ss += __shfl_xor(ss, 32, 64);
    const float sc = 1.0f / fmaxf(sqrtf(ss), 1e-6f);
    #pragma unroll
    for (int ks = 0; ks < 4; ++ks) {
      union { u16 s[8]; u16x8 u; } th;
      #pragma unroll
      for (int e = 0; e < 8; ++e) th.s[e] = f2bf(xf[ks][e] * sc);
      Ah[ks].u = th.u;
    }
  }

  // index-packed top-2 keys: key = (asint(score) & ~2047) | code_index
  int kv1[4], kv2[4];
  #pragma unroll
  for (int r = 0; r < 4; ++r) { kv1[r] = 0x80000000; kv2[r] = 0x80000000; }

  stage2x(src + 0 * 16384 + tid * 16, Bsmem + 0 * 16384 + (tid >> 6) * 1024 + 0);
  // note: dest must mirror source linearly; recompute as Bsmem + tid*16 pattern below
  // (the wave-uniform base + lane*16 layout is preserved: base = buf + w*1024, second half +8192)

  for (int t = 0; t < 32; ++t) {
    const int b = t & 1;
    asm volatile("s_waitcnt vmcnt(0)" ::: "memory");
    __builtin_amdgcn_sched_barrier(0);
    __builtin_amdgcn_s_barrier();
    __builtin_amdgcn_sched_barrier(0);
    if (t < 31)
      stage2x(src + (size_t)(t + 1) * 16384 + tid * 16, Bsmem + (b ^ 1) * 16384 + w * 1024);

    const char* base = Bsmem + b * 16384 + lane * 16;
    f32x4 acc[4];
    #pragma unroll
    for (int nf = 0; nf < 4; ++nf) acc[nf] = (f32x4){0.f, 0.f, 0.f, 0.f};

    __builtin_amdgcn_s_setprio(1);
    #pragma unroll
    for (int ks = 0; ks < 4; ++ks) {
      #pragma unroll
      for (int nf = 0; nf < 4; ++nf) {
        U8 bh;
        bh.u = *(const u16x8*)(base + ((ks * 4 + nf) << 10));
        acc[nf] = __builtin_amdgcn_mfma_f32_16x16x32_bf16(Ah[ks].b, bh.b, acc[nf], 0, 0, 0);
      }
    }
    __builtin_amdgcn_s_setprio(0);

    // epilogue: index-packed int top-2 (pure max/min tree; overlaps in-flight prefetch)
    const int base11 = t * 64 + l15;
    #pragma unroll
    for (int rg = 0; rg < 4; ++rg) {
      int kk[4];
      #pragma unroll
      for (int nf = 0; nf < 4; ++nf) {
        union { float f; int i; } cv;
        cv.f = acc[nf][rg];
        kk[nf] = (cv.i & 0xFFFFF800) | (base11 + nf * 16);
      }
      const int h1 = imax(kk[0], kk[1]), lo1 = imin(kk[0], kk[1]);
      const int h2 = imax(kk[2], kk[3]), lo2 = imin(kk[2], kk[3]);
      const int t1 = imax(h1, h2);
      const int t2 = imax(imin(h1, h2), (h1 > h2) ? lo1 : lo2);
      kv2[rg] = imax(imax(kv2[rg], t2), imin(kv1[rg], t1));
      kv1[rg] = imax(kv1[rg], t1);
    }
  }

  // ---- tail: exact refine + histograms (LDS reused) ----
  __syncthreads();
  float* apLds = (float*)Bsmem;            // [KCB] 8KB
  float* cnLds = (float*)Bsmem + KCB;      // [KCB] 8KB
  float* smr = (float*)Bsmem + 2 * KCB;    // [24]
  for (int i = tid; i < 2 * KCB; i += 512) ((float*)Bsmem)[i] = 0.0f;
  __syncthreads();

  float msum = 0.f, slat = 0.f, sent = 0.f;
  #pragma unroll
  for (int rg = 0; rg < 4; ++rg) {
    // int max of keys across the 16-lane group = bf16 max (+idx tiebreak)
    int a1k = kv1[rg];
    #pragma unroll
    for (int off = 1; off <= 8; off <<= 1) {
      const int ok = __shfl_xor(a1k, off, 64);
      a1k = ok > a1k ? ok : a1k;
    }
    const float a1val = keyval(a1k);
    const float val1 = keyval(kv1[rg]);
    const float val2 = keyval(kv2[rg]);
    const int row = row0 + w * 16 + hi * 4 + rg;
    const float mk = mask[row];
    const float add = (1.0f - mk) * 1e-6f;
    // reload x slice (8 dims/lane) + norm scale
    const float* xr = x + (size_t)row * DIMD + l15 * 8;
    const float4 xa = *(const float4*)xr;
    const float4 xb = *(const float4*)(xr + 4);
    float xs0[8] = {xa.x + add, xa.y + add, xa.z + add, xa.w + add,
                    xb.x + add, xb.y + add, xb.z + add, xb.w + add};
    float ss = 0.f;
    #pragma unroll
    for (int e = 0; e < 8; ++e) ss = fmaf(xs0[e], xs0[e], ss);
    #pragma unroll
    for (int off = 1; off <= 8; off <<= 1) ss += __shfl_xor(ss, off, 64);
    const float sc = 1.0f / fmaxf(sqrtf(ss), 1e-6f);
    // exact re-score of candidates within refine threshold of bf16 max
    const float RT = 4e-3f;
    const bool f1 = val1 > a1val - RT;
    const bool f2 = val2 > a1val - RT;
    const unsigned long long b1 = __ballot(f1);
    const unsigned long long b2 = __ballot(f2);
    unsigned m1 = (unsigned)((b1 >> (hi * 16)) & 0xFFFFull);
    unsigned m2 = (unsigned)((b2 >> (hi * 16)) & 0xFFFFull);
    float bestd = -1e30f;
    int bestk = 0x7fffffff;
    while (m1) {
      const int s = __builtin_ctz(m1); m1 &= m1 - 1;
      const int kc = __shfl(kv1[rg], (hi << 4) | s, 64) & 2047;
      const float* cr = cb + (size_t)kc * DIMD + l15 * 8;
      const float4 ca = *(const float4*)cr;
      const float4 cbv = *(const float4*)(cr + 4);
      float d = xs0[0] * ca.x;
      d = fmaf(xs0[1], ca.y, d); d = fmaf(xs0[2], ca.z, d); d = fmaf(xs0[3], ca.w, d);
      d = fmaf(xs0[4], cbv.x, d); d = fmaf(xs0[5], cbv.y, d);
      d = fmaf(xs0[6], cbv.z, d); d = fmaf(xs0[7], cbv.w, d);
      #pragma unroll
      for (int off = 1; off <= 8; off <<= 1) d += __shfl_xor(d, off, 64);
      if (d > bestd || (d == bestd && kc < bestk)) { bestd = d; bestk = kc; }
    }
    while (m2) {
      const int s = __builtin_ctz(m2); m2 &= m2 - 1;
      const int kc = __shfl(kv2[rg], (hi << 4) | s, 64) & 2047;
      const float* cr = cb + (size_t)kc * DIMD + l15 * 8;
      const float4 ca = *(const float4*)cr;
      const float4 cbv = *(const float4*)(cr + 4);
      float d = xs0[0] * ca.x;
      d = fmaf(xs0[1], ca.y, d); d = fmaf(xs0[2], ca.z, d); d = fmaf(xs0[3], ca.w, d);
      d = fmaf(xs0[4], cbv.x, d); d = fmaf(xs0[5], cbv.y, d);
      d = fmaf(xs0[6], cbv.z, d); d = fmaf(xs0[7], cbv.w, d);
      #pragma unroll
      for (int off = 1; off <= 8; off <<= 1) d += __shfl_xor(d, off, 64);
      if (d > bestd || (d == bestd && kc < bestk)) { bestd = d; bestk = kc; }
    }
    const float bestv = bestd * sc;  // exact normalized score of chosen code
    // histogram weights from bf16 per-lane top-1 (loose-threshold outputs)
    float q = 0.f, qd = 0.f;
    if (val1 > a1val - 0.055f) {
      const float d = 200.f * (val1 - a1val);
      q = __expf(d);
      qd = q * d;
    }
    float Z = q, S = qd;
    #pragma unroll
    for (int off = 1; off <= 8; off <<= 1) {
      Z += __shfl_xor(Z, off, 64);
      S += __shfl_xor(S, off, 64);
    }
    if (q > 0.f) atomicAdd(&apLds[kv1[rg] & 2047], mk * q / Z);
    // gather the exact-argmax codebook row
    const float4 g0 = *(const float4*)(cb + (size_t)bestk * DIMD + l15 * 8);
    const float4 g1 = *(const float4*)(cb + (size_t)bestk * DIMD + l15 * 8 + 4);
    *(float4*)(outQ + (size_t)row * DIMD + l15 * 8) = g0;
    *(float4*)(outQ + (size_t)row * DIMD + l15 * 8 + 4) = g1;
    if (l15 == 0) {
      atomicAdd(&cnLds[bestk], mk);
      outEnc[row] = (float)bestk;
      msum += mk;
      slat = fmaf(mk, 2.0f - 2.0f * bestv, slat);
      sent = fmaf(mk, __logf(Z) - S / Z, sent);
    }
  }
  // block-reduce the three scalars (only l15==0 lanes hold nonzero)
  #pragma unroll
  for (int off = 32; off; off >>= 1) {
    msum += __shfl_xor(msum, off, 64);
    slat += __shfl_xor(slat, off, 64);
    sent += __shfl_xor(sent, off, 64);
  }
  if (lane == 0) { smr[w * 3] = msum; smr[w * 3 + 1] = slat; smr[w * 3 + 2] = sent; }
  __syncthreads();
  if (tid == 0) {
    float t0 = 0.f, t1 = 0.f, t2 = 0.f;
    #pragma unroll
    for (int v = 0; v < 8; ++v) { t0 += smr[v * 3]; t1 += smr[v * 3 + 1]; t2 += smr[v * 3 + 2]; }
    atomicAdd(&acc4[0], t0);
    atomicAdd(&acc4[1], t1);
    atomicAdd(&acc4[2], t2);
  }
  // write per-block histogram slabs (plain coalesced stores)
  float* apDst = apPart + (size_t)blockIdx.x * KCB;
  float* cnDst = cnPart + (size_t)blockIdx.x * KCB;
  for (int i = tid; i < KCB; i += 512) {
    apDst[i] = apLds[i];
    cnDst[i] = cnLds[i];
  }
}

// reduce partial slabs -> avgp-entropy partials + outCnt. 64 blocks x 256 threads, coalesced.
__global__ __launch_bounds__(256) void k_reduce(const float* __restrict__ apPart, const float* __restrict__ cnPart,
                                                const float* __restrict__ acc4In, float* __restrict__ outCnt,
                                                float* __restrict__ acc4) {
  __shared__ float sa8[8][32];
  __shared__ float sc8[8][32];
  const int tid = threadIdx.x;
  const int kloc = tid & 31, sg = tid >> 5;
  const int k = blockIdx.x * 32 + kloc;
  float sa = 0.f, sc = 0.f;
  #pragma unroll
  for (int i = 0; i < 64; ++i) {
    const int s = sg * 64 + i;
    sa += apPart[(size_t)s * KCB + k];
    sc += cnPart[(size_t)s * KCB + k];
  }
  sa8[sg][kloc] = sa;
  sc8[sg][kloc] = sc;
  __syncthreads();
  if (tid < 32) {
    float ta = 0.f, tc = 0.f;
    #pragma unroll
    for (int g = 0; g < 8; ++g) { ta += sa8[g][tid]; tc += sc8[g][tid]; }
    outCnt[blockIdx.x * 32 + tid] = tc;
    const float a = ta / acc4In[0];
    float ae = a * __logf(a + 1e-5f);
    #pragma unroll
    for (int off = 1; off <= 16; off <<= 1) ae += __shfl_xor(ae, off, 64);
    if (tid == 0) atomicAdd(&acc4[3], ae);
  }
}

__global__ __launch_bounds__(64) void k_final(const float* __restrict__ acc4, float* __restrict__ out3) {
  if (threadIdx.x == 0) {
    const float msum = acc4[0];
    const float lat = acc4[1] / (msum + 1e-6f);
    out3[0] = lat;
    out3[1] = lat;
    out3[2] = acc4[2] / msum + acc4[3];  // sample_entropy - avg_entropy
  }
}

// ---------------- launcher ----------------

extern "C" void kernel_launch(void* const* d_in, const int* in_sizes, int n_in,
                              void* d_out, int out_size, void* d_ws, size_t ws_size,
                              hipStream_t stream) {
  const float* x = (const float*)d_in[0];
  const float* mask = (const float*)d_in[1];
  const float* cb = (const float*)d_in[2];

  float* out = (float*)d_out;
  float* outQ = out;
  float* out3 = out + (size_t)NTOK * DIMD;
  float* outCnt = out3 + 3;
  float* outEnc = outCnt + KCB;

  float* ws = (float*)d_ws;
  float* acc4 = ws;                                       // 4
  u16* cbp = (u16*)(acc4 + 8);                            // K*D u16 (512 KB, H only)
  float* apPart = (float*)(cbp + (size_t)KCB * DIMD);     // NSLAB*K (4 MB)
  float* cnPart = apPart + (size_t)NSLAB * KCB;           // NSLAB*K (4 MB)

  k_packcb<<<32768 / 256, 256, 0, stream>>>(cb, cbp, acc4);
  k_pass1<<<NTOK / 128, 512, 0, stream>>>(x, mask, cb, cbp, outQ, outEnc, apPart, cnPart, acc4);
  k_reduce<<<64, 256, 0, stream>>>(apPart, cnPart, acc4, outCnt, acc4);
  k_final<<<1, 64, 0, stream>>>(acc4, out3);
}